// Round 8
// baseline (206.106 us; speedup 1.0000x reference)
//
#include <hip/hip_runtime.h>
#include <math.h>

#define B 256
#define N 1152
#define C_ 10
#define OUT 16
#define IN 8
#define KO 160          // C_*OUT

// ---- s-partial geometry: 64-thread (1-wave) blocks, BT=4 rows/thread, all 10 k per block
#define MB 16           // batch rows per block
#define NC 9            // n per chunk
#define NCH 128         // N/NC
#define XSTR 84         // padded row stride (floats)

// partial[ch][b][k*16+o] = sum_{n in chunk} c[n,k]*(W[n,k,o,:].x[b,n,:])
__global__ __launch_bounds__(64, 4) void k_s_partial(
    const float* __restrict__ x, const float* __restrict__ W,
    const float* __restrict__ c, float* __restrict__ partial)
{
    __shared__ float xs[MB][XSTR];      // 5.4 KB
    __shared__ float cs[NC][C_];        // 360 B

    const int tid = threadIdx.x;        // 0..63
    const int id  = blockIdx.x;
    const int g   = id & 7;             // XCD
    const int q   = id >> 3;            // 0..255
    const int bt  = q & 15;             // b-tile fastest on XCD -> W reuse
    const int chl = q >> 4;             // 0..15
    const int ch  = g * 16 + chl;       // 0..127
    const int b0  = bt * MB;
    const int n0  = ch * NC;

    for (int idx = tid; idx < MB * 18; idx += 64) {
        int bl = idx / 18, r = idx - bl * 18;
        float4 val = *(const float4*)(x + (size_t)(b0 + bl) * (N * IN) + (size_t)n0 * IN + r * 4);
        *(float4*)(&xs[bl][r * 4]) = val;
    }
    if (c) {
        for (int idx = tid; idx < NC * C_; idx += 64) {
            int nl = idx / C_, k = idx - nl * C_;
            cs[nl][k] = c[(size_t)(n0 + nl) * C_ + k];
        }
    }
    __syncthreads();

    const int o   = tid & 15;
    const int grp = (tid >> 4) * 4;     // rows grp..grp+3

    float acc[4][C_];
#pragma unroll
    for (int r = 0; r < 4; ++r)
#pragma unroll
        for (int k = 0; k < C_; ++k) acc[r][k] = 0.f;

    const float* Wb = W + (size_t)n0 * (KO * IN) + o * IN;

    for (int nl = 0; nl < NC; ++nl) {
        float4 xr[4][2];
#pragma unroll
        for (int r = 0; r < 4; ++r) {
            xr[r][0] = *(const float4*)(&xs[grp + r][nl * IN]);
            xr[r][1] = *(const float4*)(&xs[grp + r][nl * IN + 4]);
        }
        float cw[C_];
#pragma unroll
        for (int k = 0; k < C_; ++k) cw[k] = c ? cs[nl][k] : 0.1f;

        const float* Wn = Wb + (size_t)nl * (KO * IN);
#pragma unroll
        for (int k = 0; k < C_; ++k) {
            float4 w0 = *(const float4*)(Wn + k * (OUT * IN));
            float4 w1 = *(const float4*)(Wn + k * (OUT * IN) + 4);
#pragma unroll
            for (int r = 0; r < 4; ++r) {
                float d = w0.x * xr[r][0].x + w0.y * xr[r][0].y
                        + w0.z * xr[r][0].z + w0.w * xr[r][0].w
                        + w1.x * xr[r][1].x + w1.y * xr[r][1].y
                        + w1.z * xr[r][1].z + w1.w * xr[r][1].w;
                acc[r][k] += cw[k] * d;
            }
        }
    }

#pragma unroll
    for (int r = 0; r < 4; ++r) {
        float* pp = partial + (size_t)ch * (B * KO) + (size_t)(b0 + grp + r) * KO + o;
#pragma unroll
        for (int k = 0; k < C_; ++k) pp[k * OUT] = acc[r][k];
    }
}

// ---------------- reduce partials over 128 chunks + squash
__global__ __launch_bounds__(256) void k_reduce_squash(
    const float* __restrict__ partial, float* __restrict__ v, float* __restrict__ out)
{
    __shared__ float red[256];
    const int tid = threadIdx.x;
    const int e   = blockIdx.x * 64 + (tid & 63);   // element 0..40959
    const int q   = tid >> 6;                       // wave 0..3
    float s = 0.f;
#pragma unroll
    for (int i = 0; i < NCH / 4; ++i)
        s += partial[(size_t)(q * (NCH / 4) + i) * (B * KO) + e];
    red[tid] = s;
    __syncthreads();
    if (q == 0) {
        s = red[tid] + red[tid + 64] + red[tid + 128] + red[tid + 192];
        float vv = s * fabsf(s) / (1.f + s * s);
        v[e] = vv;
        if (out) out[e] = vv;
    }
}

// ---------------- a-partial: pa[bt*4+grp][n][k] = sum_{b in 4 rows, o} (W[n,k,o,:].x[b,n,:]) * v[b,k,o]
// Same access structure as k_s_partial (coalesced x rows, W streamed via L2, bt fastest
// per XCD). v tile in LDS (stride 164 -> only free 2-way conflicts). In-wave shfl
// reduction over o; 4 lanes write 30 partials each. Replaces R7's transposed-gather k_a_sm.
#define NCA 3
#define NCHA 384        // N/NCA
__global__ __launch_bounds__(64, 4) void k_a_partial(
    const float* __restrict__ x, const float* __restrict__ W,
    const float* __restrict__ v, float* __restrict__ pa)
{
    __shared__ float xs[MB][28];        // 16 x 28 floats = 1.75 KB
    __shared__ float vs[MB][164];       // 10.25 KB

    const int tid = threadIdx.x;        // 0..63
    const int id  = blockIdx.x;
    const int g   = id & 7;             // XCD
    const int q   = id >> 3;            // 0..767
    const int bt  = q & 15;             // b-tile fastest -> W reuse on XCD
    const int chl = q >> 4;             // 0..47
    const int ch  = g * 48 + chl;       // 0..383
    const int b0  = bt * MB;
    const int n0  = ch * NCA;

    // stage x: 16 rows x 6 float4 (24 contiguous floats)
    for (int idx = tid; idx < MB * 6; idx += 64) {
        int bl = idx / 6, r = idx - bl * 6;
        float4 val = *(const float4*)(x + (size_t)(b0 + bl) * (N * IN) + (size_t)n0 * IN + r * 4);
        *(float4*)(&xs[bl][r * 4]) = val;
    }
    // stage v: 16 rows x 40 float4 (160 contiguous floats)
    for (int idx = tid; idx < MB * 40; idx += 64) {
        int bl = idx / 40, r = idx - bl * 40;
        float4 val = *(const float4*)(v + (size_t)(b0 + bl) * KO + r * 4);
        *(float4*)(&vs[bl][r * 4]) = val;
    }
    __syncthreads();

    const int o    = tid & 15;
    const int grp  = tid >> 4;          // 0..3
    const int row0 = grp * 4;

    float acc[NCA][C_];
#pragma unroll
    for (int nl = 0; nl < NCA; ++nl)
#pragma unroll
        for (int k = 0; k < C_; ++k) acc[nl][k] = 0.f;

    const float* Wb = W + (size_t)n0 * (KO * IN) + o * IN;

#pragma unroll
    for (int nl = 0; nl < NCA; ++nl) {
        float4 xr[4][2];
#pragma unroll
        for (int r = 0; r < 4; ++r) {
            xr[r][0] = *(const float4*)(&xs[row0 + r][nl * IN]);
            xr[r][1] = *(const float4*)(&xs[row0 + r][nl * IN + 4]);
        }
        const float* Wn = Wb + (size_t)nl * (KO * IN);
#pragma unroll
        for (int k = 0; k < C_; ++k) {
            float4 w0 = *(const float4*)(Wn + k * (OUT * IN));
            float4 w1 = *(const float4*)(Wn + k * (OUT * IN) + 4);
#pragma unroll
            for (int r = 0; r < 4; ++r) {
                float d = w0.x * xr[r][0].x + w0.y * xr[r][0].y
                        + w0.z * xr[r][0].z + w0.w * xr[r][0].w
                        + w1.x * xr[r][1].x + w1.y * xr[r][1].y
                        + w1.z * xr[r][1].z + w1.w * xr[r][1].w;
                acc[nl][k] += d * vs[row0 + r][k * OUT + o];
            }
        }
    }

    // reduce over the 16 o-lanes within each 16-lane group (static indices only)
#pragma unroll
    for (int nl = 0; nl < NCA; ++nl)
#pragma unroll
        for (int k = 0; k < C_; ++k) {
            float s = acc[nl][k];
            s += __shfl_xor(s, 1);
            s += __shfl_xor(s, 2);
            s += __shfl_xor(s, 4);
            s += __shfl_xor(s, 8);
            acc[nl][k] = s;
        }
    if ((tid & 15) == 0) {
        float* pp = pa + ((size_t)(bt * 4 + grp)) * (N * C_) + (size_t)n0 * C_;
#pragma unroll
        for (int nl = 0; nl < NCA; ++nl)
#pragma unroll
            for (int k = 0; k < C_; ++k) pp[nl * C_ + k] = acc[nl][k];
    }
}

// ---------------- bij update + softmax: reduce pa over 64 slices
// grid 36 x 320: thread = one (n,k); 32 n per block
__global__ __launch_bounds__(320) void k_bij_sm(
    const float* __restrict__ pa, float* __restrict__ bij,
    float* __restrict__ c_out, int accumulate)
{
    __shared__ float bs[32][11];
    const int t  = threadIdx.x;         // 0..319
    const int nl = t / C_;
    const int k  = t - nl * C_;
    const int n  = blockIdx.x * 32 + nl;

    float a = 0.f;
#pragma unroll
    for (int j = 0; j < 64; ++j)
        a += pa[(size_t)j * (N * C_) + (size_t)n * C_ + k];
    a *= (1.0f / B);
    float bn = (accumulate ? bij[(size_t)n * C_ + k] : 0.f) + a;
    bij[(size_t)n * C_ + k] = bn;
    bs[nl][k] = bn;
    __syncthreads();

    float m = -1e30f;
#pragma unroll
    for (int kk = 0; kk < C_; ++kk) m = fmaxf(m, bs[nl][kk]);
    float ssum = 0.f;
#pragma unroll
    for (int kk = 0; kk < C_; ++kk) ssum += __expf(bs[nl][kk] - m);
    c_out[(size_t)n * C_ + k] = __expf(bn - m) / ssum;
}

extern "C" void kernel_launch(void* const* d_in, const int* in_sizes, int n_in,
                              void* d_out, int out_size, void* d_ws, size_t ws_size,
                              hipStream_t stream)
{
    const float* x = (const float*)d_in[0];   // [B, N, IN]
    const float* W = (const float*)d_in[1];   // [1, N, C, OUT, IN]
    float* out = (float*)d_out;               // [B, C, OUT, 1] = 40960 floats
    float* ws  = (float*)d_ws;

    float* part = ws;                         // 128 * 40960 = 5242880 floats (21 MB)
    float* bij  = ws + 5242880;               // 11520
    float* c    = bij + 11520;                // 11520
    float* v    = c + 11520;                  // 40960
    float* pa   = v + 40960;                  // 64 * 11520 = 737280

    const int GS  = 2048;
    const int GSA = 6144;

    // iteration 0: c = 1/C exactly (softmax of zeros)
    k_s_partial<<<GS, 64, 0, stream>>>(x, W, nullptr, part);
    k_reduce_squash<<<640, 256, 0, stream>>>(part, v, nullptr);
    k_a_partial<<<GSA, 64, 0, stream>>>(x, W, v, pa);
    k_bij_sm<<<36, 320, 0, stream>>>(pa, bij, c, 0);

    // iteration 1
    k_s_partial<<<GS, 64, 0, stream>>>(x, W, c, part);
    k_reduce_squash<<<640, 256, 0, stream>>>(part, v, nullptr);
    k_a_partial<<<GSA, 64, 0, stream>>>(x, W, v, pa);
    k_bij_sm<<<36, 320, 0, stream>>>(pa, bij, c, 1);

    // iteration 2 (final: write d_out)
    k_s_partial<<<GS, 64, 0, stream>>>(x, W, c, part);
    k_reduce_squash<<<640, 256, 0, stream>>>(part, v, out);
}